// Round 14
// baseline (397.903 us; speedup 1.0000x reference)
//
#include <hip/hip_runtime.h>

typedef unsigned short ushort_t;
typedef unsigned int uint32;
typedef __bf16 bf16x8 __attribute__((ext_vector_type(8)));
typedef float f32x4 __attribute__((ext_vector_type(4)));
typedef float f32x16 __attribute__((ext_vector_type(16)));

#define MFMA16(a, b, c) __builtin_amdgcn_mfma_f32_16x16x32_bf16((a), (b), (c), 0, 0, 0)
#define MFMA32(a, b, c) __builtin_amdgcn_mfma_f32_32x32x16_bf16((a), (b), (c), 0, 0, 0)

__device__ __forceinline__ ushort_t f2bf(float f) {
  union { float f; uint32 u; } c; c.f = f;
  uint32 u = c.u;
  u += 0x7fffu + ((u >> 16) & 1u);   // round-to-nearest-even
  return (ushort_t)(u >> 16);
}

// async global->LDS, 16B per lane. LDS dest must be wave-uniform base + lane*16.
__device__ __forceinline__ void gload_lds16(const void* g, void* l) {
  __builtin_amdgcn_global_load_lds(
      (const __attribute__((address_space(1))) void*)g,
      (__attribute__((address_space(3))) void*)l, 16, 0, 0);
}

// ---------------------------------------------------------------------------
// Fused fp32->bf16 convert of all 5 tensors (outputs contiguous in ws).
// ---------------------------------------------------------------------------
__global__ __launch_bounds__(256)
void cvt5_kernel(const float* __restrict__ p0, const float* __restrict__ p1,
                 const float* __restrict__ p2, const float* __restrict__ p3,
                 const float* __restrict__ p4, ushort_t* __restrict__ out) {
  const size_t B0 = 12582912;              // hs        [4096x3072]
  const size_t B1 = B0 + 9437184;          // Wq        [3072x3072]
  const size_t B2 = B1 + 3145728;          // Wk        [1024x3072]
  const size_t B3 = B2 + 3145728;          // Wv        [1024x3072]
  const size_t B4 = B3 + 9437184;          // Wd        [3072x3072]
  const size_t step = (size_t)gridDim.x * 256 * 4;
  for (size_t g = ((size_t)blockIdx.x * 256 + threadIdx.x) * 4; g < B4; g += step) {
    const float* src; size_t off;
    if (g < B0)      { src = p0; off = 0;  }
    else if (g < B1) { src = p1; off = B0; }
    else if (g < B2) { src = p2; off = B1; }
    else if (g < B3) { src = p3; off = B2; }
    else             { src = p4; off = B3; }
    float4 v = *(const float4*)(src + (g - off));
    union { uint2 u; ushort_t s[4]; } p;
    p.s[0] = f2bf(v.x); p.s[1] = f2bf(v.y);
    p.s[2] = f2bf(v.z); p.s[3] = f2bf(v.w);
    *(uint2*)(out + g) = p.u;
  }
}

// ===========================================================================
// 2-phase GEMM body, 32x32x16 MFMA: 128x128 tile, BK=64, 4 waves (2x2),
// per-wave 64x64 = 2x2 tiles of 32x32. Staging identical to round-10
// (gload_lds width-16, XOR-swizzled via pre-swizzled source).
// A/B frag: row|col = lane&31, k = (lane>>5)*8 + j  [m74/m101 family].
// C/D frag: col = lane&31, row = (reg&3) + 8*(reg>>2) + 4*(lane>>5).
// ===========================================================================
#define GEMM_BODY32(ABASE, WROWBASE, KD)                                        \
  f32x16 acc[2][2] = {};                                                        \
  const int l31 = lane & 31;                                                    \
  const int khb = (lane >> 5) << 4;  /* k-half byte offset: 0 or 16 */          \
  const int nk = (KD) >> 6;                                                     \
  for (int kt = 0; kt < nk; ++kt) {                                             \
    _Pragma("unroll")                                                           \
    for (int i = 0; i < 4; ++i) {                                               \
      int o = (i * 256 + tid) * 16;                                             \
      int row = o >> 7;                                                         \
      int src = (o & 127) ^ ((row & 7) << 4);                                   \
      gload_lds16(ABASE + (rowA0 + row) * (KD) + kt * 64 + (src >> 1),          \
                  (char*)As + o);                                               \
      gload_lds16(WROWBASE + (size_t)row * (KD) + kt * 64 + (src >> 1),         \
                  (char*)Bs + o);                                               \
    }                                                                           \
    __syncthreads();                                                            \
    _Pragma("unroll")                                                           \
    for (int ks = 0; ks < 4; ++ks) {                                            \
      bf16x8 af[2], bfr[2];                                                     \
      _Pragma("unroll")                                                         \
      for (int mi = 0; mi < 2; ++mi) {                                          \
        int ar = wr * 64 + mi * 32 + l31;                                       \
        int off = ar * 128 + ((ks * 32 + khb) ^ ((ar & 7) << 4));               \
        af[mi] = *(const bf16x8*)((const char*)As + off);                       \
      }                                                                         \
      _Pragma("unroll")                                                         \
      for (int nj = 0; nj < 2; ++nj) {                                          \
        int br = wc * 64 + nj * 32 + l31;                                       \
        int off = br * 128 + ((ks * 32 + khb) ^ ((br & 7) << 4));               \
        bfr[nj] = *(const bf16x8*)((const char*)Bs + off);                      \
      }                                                                         \
      _Pragma("unroll")                                                         \
      for (int mi = 0; mi < 2; ++mi)                                            \
        _Pragma("unroll")                                                       \
        for (int nj = 0; nj < 2; ++nj)                                          \
          acc[mi][nj] = MFMA32(af[mi], bfr[nj], acc[mi][nj]);                   \
    }                                                                           \
    __syncthreads();                                                            \
  }

// ---------------------------------------------------------------------------
// Fused QKV GEMM: C[4096,5120], grid = 1280, XCD 2D chunk 16x10.
// ---------------------------------------------------------------------------
__global__ __launch_bounds__(256)
void qkv_gemm_kernel(const ushort_t* __restrict__ A,
                     const ushort_t* __restrict__ Wq, const ushort_t* __restrict__ Wk,
                     const ushort_t* __restrict__ Wv,
                     const float* __restrict__ bq, const float* __restrict__ bk,
                     const float* __restrict__ bv, ushort_t* __restrict__ C)
{
  __shared__ __attribute__((aligned(16))) ushort_t As[128 * 64];
  __shared__ __attribute__((aligned(16))) ushort_t Bs[128 * 64];
  const int tid = threadIdx.x;
  const int lane = tid & 63;
  const int wv_ = tid >> 6;
  const int wr = wv_ >> 1, wc = wv_ & 1;
  const int x = blockIdx.x & 7;
  const int li = blockIdx.x >> 3;
  const int bm = ((x & 1) << 4) | (li & 15);
  const int bn = (x >> 1) * 10 + (li >> 4);

  const ushort_t* Wsrc; const float* bsrc; int nloc;
  if (bn < 24)      { Wsrc = Wq; bsrc = bq; nloc = bn << 7; }
  else if (bn < 32) { Wsrc = Wk; bsrc = bk; nloc = (bn - 24) << 7; }
  else              { Wsrc = Wv; bsrc = bv; nloc = (bn - 32) << 7; }

  const size_t rowA0 = (size_t)bm * 128;
  const ushort_t* Wrow = Wsrc + (size_t)nloc * 3072;

  GEMM_BODY32(A, Wrow, 3072)

  // epilogue: 32x32 C/D layout col=l31, row=(r&3)+8*(r>>2)+4*(lane>>5)
  const int rhi = (lane >> 5) << 2;
#pragma unroll
  for (int nj = 0; nj < 2; ++nj) {
    int cl = wc * 64 + nj * 32 + l31;
    float bvl = bsrc[nloc + cl];
    int col = bn * 128 + cl;
#pragma unroll
    for (int mi = 0; mi < 2; ++mi) {
      int row0 = bm * 128 + wr * 64 + mi * 32 + rhi;
#pragma unroll
      for (int r = 0; r < 16; ++r) {
        int rowl = (r & 3) + 8 * (r >> 2);
        C[(size_t)(row0 + rowl) * 5120 + col] = f2bf(acc[mi][nj][r] + bvl);
      }
    }
  }
}

// ---------------------------------------------------------------------------
// Generic single-weight GEMM (out-proj). XCD 2D chunk 16 x cbn.
// ---------------------------------------------------------------------------
template <bool OUT_F32>
__global__ __launch_bounds__(256)
void gemm_bt_kernel(const ushort_t* __restrict__ A, const ushort_t* __restrict__ W,
                    const float* __restrict__ bias, void* __restrict__ Cv,
                    int N, int Kd, int cbn)
{
  __shared__ __attribute__((aligned(16))) ushort_t As[128 * 64];
  __shared__ __attribute__((aligned(16))) ushort_t Bs[128 * 64];
  const int tid = threadIdx.x;
  const int lane = tid & 63;
  const int wv_ = tid >> 6;
  const int wr = wv_ >> 1, wc = wv_ & 1;
  const int x = blockIdx.x & 7;
  const int li = blockIdx.x >> 3;
  const int bm = ((x & 1) << 4) | (li & 15);
  const int bn = (x >> 1) * cbn + (li >> 4);

  const size_t rowA0 = (size_t)bm * 128;
  const ushort_t* Wrow = W + (size_t)(bn * 128) * Kd;

  GEMM_BODY32(A, Wrow, Kd)

  const int rhi = (lane >> 5) << 2;
#pragma unroll
  for (int nj = 0; nj < 2; ++nj) {
    int col = bn * 128 + wc * 64 + nj * 32 + l31;
    float bvl = bias[col];
#pragma unroll
    for (int mi = 0; mi < 2; ++mi) {
      int row0 = bm * 128 + wr * 64 + mi * 32 + rhi;
#pragma unroll
      for (int r = 0; r < 16; ++r) {
        int rowl = (r & 3) + 8 * (r >> 2);
        float v = acc[mi][nj][r] + bvl;
        if (OUT_F32) ((float*)Cv)[(size_t)(row0 + rowl) * N + col] = v;
        else         ((ushort_t*)Cv)[(size_t)(row0 + rowl) * N + col] = f2bf(v);
      }
    }
  }
}

// ---------------------------------------------------------------------------
// Flash attention (round-10, frozen): swapped QK^T, dbuf-K gload_lds, V-reg
// transpose, in-register exp2 softmax + defer-max, shfl-P, unpaired grid.
// ---------------------------------------------------------------------------
#define NHEADS 24
#define GRP 3
#define SEQ 2048
#define QSCL 0.12751745f   // HD^-0.5 * log2(e)
#define DTHR 8.0f          // defer-max threshold (exp2 domain): P <= 2^8

__global__ __launch_bounds__(256)
void attn_kernel(const ushort_t* __restrict__ QKV, ushort_t* __restrict__ O)
{
  __shared__ __attribute__((aligned(16))) ushort_t Kl[2][64 * 128]; // swizzled [kv][d]
  __shared__ __attribute__((aligned(16))) ushort_t Vt[128 * 64];    // swizzled [d][kv]

  const int tid = threadIdx.x;
  const int lane = tid & 63;
  const int wv = tid >> 6;
  const int l15 = lane & 15, lg = lane >> 4;
  const int bh = blockIdx.x;
  const int qb = 31 - blockIdx.y;      // longest blocks dispatch first
  const int b = bh / NHEADS, h = bh % NHEADS;
  const int kvh = h / GRP;
  const size_t kbase = (size_t)b * SEQ * 5120 + 3072 + (size_t)kvh * 128;
  const size_t vbase = kbase + 1024;
  const int q0 = qb * 64;

  const int kv4 = (tid & 15) * 4;      // V staging: 4 kv rows x 8 d per thread
  const int d8 = (tid >> 4) * 8;
  const int a_sel = lg >> 1;
  const int s0l = (lane & 15) + 32 * (lg & 1);

  // ---- prologue: K(0) -> Kl[0] (async), V(0) -> regs ----
#pragma unroll
  for (int i = 0; i < 4; ++i) {
    int o = (i * 256 + tid) * 16;
    int row = o >> 8;
    int src = (o & 255) ^ ((row & 7) << 4);
    gload_lds16(QKV + kbase + (size_t)row * 5120 + (src >> 1), (char*)&Kl[0][0] + o);
  }
  uint4 vr0, vr1, vr2, vr3;
  {
    const ushort_t* vg = QKV + vbase + (size_t)kv4 * 5120 + d8;
    vr0 = *(const uint4*)(vg);
    vr1 = *(const uint4*)(vg + 5120);
    vr2 = *(const uint4*)(vg + 10240);
    vr3 = *(const uint4*)(vg + 15360);
  }

  // Q fragments, pre-scaled by SCALE*log2e
  bf16x8 qf[4];
  {
    const ushort_t* qg = QKV + (size_t)(b * SEQ + q0 + wv * 16 + l15) * 5120 + h * 128 + lg * 8;
#pragma unroll
    for (int c = 0; c < 4; ++c) {
      bf16x8 q = *(const bf16x8*)(qg + c * 32);
#pragma unroll
      for (int e = 0; e < 8; ++e) q[e] = (__bf16)((float)q[e] * QSCL);
      qf[c] = q;
    }
  }

  float m_st = -1e30f, l_st = 0.f;
  f32x4 accO[8] = {};

  for (int t = 0; t <= qb; ++t) {
    const int cur = t & 1;
    // ---- V(t) regs -> Vt (transposed, swizzled) ----
    {
      union { uint4 u; ushort_t s[8]; } L0, L1, L2, L3;
      L0.u = vr0; L1.u = vr1; L2.u = vr2; L3.u = vr3;
#pragma unroll
      for (int dd = 0; dd < 8; ++dd) {
        int d = d8 + dd;
        uint2 w;
        w.x = (uint32)L0.s[dd] | ((uint32)L1.s[dd] << 16);
        w.y = (uint32)L2.s[dd] | ((uint32)L3.s[dd] << 16);
        int swz = ((d & 7) ^ ((d >> 3) & 3)) << 4;
        int off = (d * 128 + kv4 * 2) ^ swz;
        *(uint2*)((char*)Vt + off) = w;
      }
    }
    asm volatile("s_waitcnt lgkmcnt(0)" ::: "memory");
    __builtin_amdgcn_s_barrier();      // Kl[cur] + Vt ready; no vmcnt drain

    // ---- prefetch tile t+1 across the compute phase ----
    if (t < qb) {
      const int kvn = (t + 1) * 64;
#pragma unroll
      for (int i = 0; i < 4; ++i) {
        int o = (i * 256 + tid) * 16;
        int row = o >> 8;
        int src = (o & 255) ^ ((row & 7) << 4);
        gload_lds16(QKV + kbase + (size_t)(kvn + row) * 5120 + (src >> 1),
                    (char*)&Kl[cur ^ 1][0] + o);
      }
      const ushort_t* vg = QKV + vbase + (size_t)(kvn + kv4) * 5120 + d8;
      vr0 = *(const uint4*)(vg);
      vr1 = *(const uint4*)(vg + 5120);
      vr2 = *(const uint4*)(vg + 10240);
      vr3 = *(const uint4*)(vg + 15360);
    }

    // ---- QK^T swapped: s[n] = S^T tile ----
    f32x4 s[4];
    __builtin_amdgcn_s_setprio(1);
#pragma unroll
    for (int n = 0; n < 4; ++n) {
      f32x4 z = {0.f, 0.f, 0.f, 0.f};
      s[n] = z;
#pragma unroll
      for (int c = 0; c < 4; ++c) {
        int row = n * 16 + l15;
        int boff = (row * 256 + c * 64 + lg * 16) ^ ((row & 7) << 4);
        bf16x8 kf = *(const bf16x8*)((const char*)Kl[cur] + boff);
        s[n] = MFMA16(kf, qf[c], s[n]);   // A=K, B=Q -> S^T
      }
    }
    __builtin_amdgcn_s_setprio(0);

    // causal mask (diag tile): kv = 16n+4lg+r vs q-rel = wv*16+l15
    if (t == qb) {
      const int qg_ = wv * 16 + l15;
#pragma unroll
      for (int n = 0; n < 4; ++n)
#pragma unroll
        for (int r = 0; r < 4; ++r)
          if (n * 16 + lg * 4 + r > qg_) s[n][r] = -1e9f;
    }

    // ---- softmax (exp2 domain) with defer-max (T13) ----
    float mx = fmaxf(fmaxf(fmaxf(s[0][0], s[0][1]), fmaxf(s[0][2], s[0][3])),
                     fmaxf(fmaxf(s[1][0], s[1][1]), fmaxf(s[1][2], s[1][3])));
    mx = fmaxf(mx, fmaxf(fmaxf(fmaxf(s[2][0], s[2][1]), fmaxf(s[2][2], s[2][3])),
                         fmaxf(fmaxf(s[3][0], s[3][1]), fmaxf(s[3][2], s[3][3]))));
    mx = fmaxf(mx, __shfl_xor(mx, 16, 64));
    mx = fmaxf(mx, __shfl_xor(mx, 32, 64));

    if (!__all(mx <= m_st + DTHR)) {   // wave-uniform rescale (rare after tile 0)
      const float mnew = fmaxf(m_st, mx);
      const float alpha = __builtin_amdgcn_exp2f(m_st - mnew);
      m_st = mnew;
      l_st *= alpha;
#pragma unroll
      for (int j = 0; j < 8; ++j)
#pragma unroll
        for (int r = 0; r < 4; ++r) accO[j][r] *= alpha;
    }

    float rsum = 0.f;
    uint32 dwA[4], dwB[4];
#pragma unroll
    for (int n = 0; n < 4; ++n) {
      float p0 = __builtin_amdgcn_exp2f(s[n][0] - m_st);
      float p1 = __builtin_amdgcn_exp2f(s[n][1] - m_st);
      float p2 = __builtin_amdgcn_exp2f(s[n][2] - m_st);
      float p3 = __builtin_amdgcn_exp2f(s[n][3] - m_st);
      rsum += (p0 + p1) + (p2 + p3);
      dwA[n] = (uint32)f2bf(p0) | ((uint32)f2bf(p1) << 16);
      dwB[n] = (uint32)f2bf(p2) | ((uint32)f2bf(p3) << 16);
    }
    rsum += __shfl_xor(rsum, 16, 64);
    rsum += __shfl_xor(rsum, 32, 64);
    l_st += rsum;

    // ---- PV: accO[j] += mfma(Vt-frag, P^T-frag) ----
#pragma unroll
    for (int c = 0; c < 2; ++c) {
      uint32 xA0 = __shfl((int)dwA[2 * c],     s0l,      64);
      uint32 xB0 = __shfl((int)dwB[2 * c],     s0l,      64);
      uint32 xA1 = __shfl((int)dwA[2 * c + 1], s0l,      64);
      uint32 xB1 = __shfl((int)dwB[2 * c + 1], s0l,      64);
      uint32 yA0 = __shfl((int)dwA[2 * c],     s0l + 16, 64);
      uint32 yB0 = __shfl((int)dwB[2 * c],     s0l + 16, 64);
      uint32 yA1 = __shfl((int)dwA[2 * c + 1], s0l + 16, 64);
      uint32 yB1 = __shfl((int)dwB[2 * c + 1], s0l + 16, 64);
      union { uint4 u; bf16x8 v; } pb;
      pb.u.x = a_sel ? xA1 : xA0;
      pb.u.y = a_sel ? xB1 : xB0;
      pb.u.z = a_sel ? yA1 : yA0;
      pb.u.w = a_sel ? yB1 : yB0;
      __builtin_amdgcn_s_setprio(1);
#pragma unroll
      for (int j = 0; j < 8; ++j) {
        int d = j * 16 + l15;
        int swz = ((d & 7) ^ ((d >> 3) & 3)) << 4;
        int off = (d * 128 + c * 64 + lg * 16) ^ swz;
        bf16x8 vf = *(const bf16x8*)((const char*)Vt + off);
        accO[j] = MFMA16(vf, pb.v, accO[j]);  // A=V^T, B=P^T -> O^T
      }
      __builtin_amdgcn_s_setprio(0);
    }
    __builtin_amdgcn_s_barrier();   // all waves done reading Kl[cur]/Vt
  }

  // ---- epilogue: O^T layout (d = 16j+4lg+r, q col = l15) ----
  const float inv = 1.0f / l_st;
  ushort_t* og = O + (size_t)(b * SEQ + q0 + wv * 16 + l15) * 3072 + h * 128 + lg * 4;
#pragma unroll
  for (int j = 0; j < 8; ++j) {
    union { uint2 u; ushort_t s[4]; } w;
    w.s[0] = f2bf(accO[j][0] * inv);
    w.s[1] = f2bf(accO[j][1] * inv);
    w.s[2] = f2bf(accO[j][2] * inv);
    w.s[3] = f2bf(accO[j][3] * inv);
    *(uint2*)(og + j * 16) = w.u;
  }
}

// ---------------------------------------------------------------------------
extern "C" void kernel_launch(void* const* d_in, const int* in_sizes, int n_in,
                              void* d_out, int out_size, void* d_ws, size_t ws_size,
                              hipStream_t stream) {
  const float* hs = (const float*)d_in[0];
  // d_in[1] = attention_mask (causal by construction; applied analytically)
  const float* Wq = (const float*)d_in[2];
  const float* bq = (const float*)d_in[3];
  const float* Wk = (const float*)d_in[4];
  const float* bk = (const float*)d_in[5];
  const float* Wv = (const float*)d_in[6];
  const float* bv = (const float*)d_in[7];
  const float* Wd = (const float*)d_in[8];
  const float* bd = (const float*)d_in[9];
  float* out = (float*)d_out;

  const size_t N_HS = (size_t)4096 * 3072;
  const size_t N_WQ = (size_t)3072 * 3072;
  const size_t N_WK = (size_t)1024 * 3072;

  ushort_t* hs_bf = (ushort_t*)d_ws;
  ushort_t* Wq_bf = hs_bf + N_HS;
  ushort_t* Wk_bf = Wq_bf + N_WQ;
  ushort_t* Wv_bf = Wk_bf + N_WK;
  ushort_t* Wd_bf = Wv_bf + N_WK;
  ushort_t* QKVw  = Wd_bf + N_WQ;             // [4096, 5120]
  ushort_t* Cw    = hs_bf;                    // ctx aliases hs_bf

  cvt5_kernel<<<dim3(2048), dim3(256), 0, stream>>>(hs, Wq, Wk, Wv, Wd, hs_bf);
  qkv_gemm_kernel<<<dim3(1280), dim3(256), 0, stream>>>(hs_bf, Wq_bf, Wk_bf, Wv_bf,
                                                        bq, bk, bv, QKVw);
  attn_kernel<<<dim3(48, 32), dim3(256), 0, stream>>>(QKVw, Cw);
  gemm_bt_kernel<true><<<dim3(24 * 32), dim3(256), 0, stream>>>(Cw, Wd_bf, bd, out,
                                                                3072, 3072, 6);
}

// Round 15
// 379.765 us; speedup vs baseline: 1.0478x; 1.0478x over previous
//
#include <hip/hip_runtime.h>

typedef unsigned short ushort_t;
typedef unsigned int uint32;
typedef __bf16 bf16x8 __attribute__((ext_vector_type(8)));
typedef float f32x4 __attribute__((ext_vector_type(4)));
typedef float f32x16 __attribute__((ext_vector_type(16)));

#define MFMA16(a, b, c) __builtin_amdgcn_mfma_f32_16x16x32_bf16((a), (b), (c), 0, 0, 0)
#define MFMA32(a, b, c) __builtin_amdgcn_mfma_f32_32x32x16_bf16((a), (b), (c), 0, 0, 0)

__device__ __forceinline__ ushort_t f2bf(float f) {
  union { float f; uint32 u; } c; c.f = f;
  uint32 u = c.u;
  u += 0x7fffu + ((u >> 16) & 1u);   // round-to-nearest-even
  return (ushort_t)(u >> 16);
}

// async global->LDS, 16B per lane. LDS dest must be wave-uniform base + lane*16.
__device__ __forceinline__ void gload_lds16(const void* g, void* l) {
  __builtin_amdgcn_global_load_lds(
      (const __attribute__((address_space(1))) void*)g,
      (__attribute__((address_space(3))) void*)l, 16, 0, 0);
}

// ---------------------------------------------------------------------------
// Fused fp32->bf16 convert of all 5 tensors (outputs contiguous in ws).
// ---------------------------------------------------------------------------
__global__ __launch_bounds__(256)
void cvt5_kernel(const float* __restrict__ p0, const float* __restrict__ p1,
                 const float* __restrict__ p2, const float* __restrict__ p3,
                 const float* __restrict__ p4, ushort_t* __restrict__ out) {
  const size_t B0 = 12582912;              // hs        [4096x3072]
  const size_t B1 = B0 + 9437184;          // Wq        [3072x3072]
  const size_t B2 = B1 + 3145728;          // Wk        [1024x3072]
  const size_t B3 = B2 + 3145728;          // Wv        [1024x3072]
  const size_t B4 = B3 + 9437184;          // Wd        [3072x3072]
  const size_t step = (size_t)gridDim.x * 256 * 4;
  for (size_t g = ((size_t)blockIdx.x * 256 + threadIdx.x) * 4; g < B4; g += step) {
    const float* src; size_t off;
    if (g < B0)      { src = p0; off = 0;  }
    else if (g < B1) { src = p1; off = B0; }
    else if (g < B2) { src = p2; off = B1; }
    else if (g < B3) { src = p3; off = B2; }
    else             { src = p4; off = B3; }
    float4 v = *(const float4*)(src + (g - off));
    union { uint2 u; ushort_t s[4]; } p;
    p.s[0] = f2bf(v.x); p.s[1] = f2bf(v.y);
    p.s[2] = f2bf(v.z); p.s[3] = f2bf(v.w);
    *(uint2*)(out + g) = p.u;
  }
}

// ===========================================================================
// 2-phase GEMM body, 32x32x16 MFMA: 128x128 tile, BK=64, 4 waves (2x2),
// per-wave 64x64 = 2x2 tiles of 32x32. Staging identical to round-10
// (gload_lds width-16, XOR-swizzled via pre-swizzled source).
// A/B frag: row|col = lane&31, k = (lane>>5)*8 + j  [m74/m101 family].
// C/D frag: col = lane&31, row = (reg&3) + 8*(reg>>2) + 4*(lane>>5).
// ===========================================================================
#define GEMM_BODY32(ABASE, WROWBASE, KD)                                        \
  f32x16 acc[2][2] = {};                                                        \
  const int l31 = lane & 31;                                                    \
  const int khb = (lane >> 5) << 4;  /* k-half byte offset: 0 or 16 */          \
  const int nk = (KD) >> 6;                                                     \
  for (int kt = 0; kt < nk; ++kt) {                                             \
    _Pragma("unroll")                                                           \
    for (int i = 0; i < 4; ++i) {                                               \
      int o = (i * 256 + tid) * 16;                                             \
      int row = o >> 7;                                                         \
      int src = (o & 127) ^ ((row & 7) << 4);                                   \
      gload_lds16(ABASE + (rowA0 + row) * (KD) + kt * 64 + (src >> 1),          \
                  (char*)As + o);                                               \
      gload_lds16(WROWBASE + (size_t)row * (KD) + kt * 64 + (src >> 1),         \
                  (char*)Bs + o);                                               \
    }                                                                           \
    __syncthreads();                                                            \
    _Pragma("unroll")                                                           \
    for (int ks = 0; ks < 4; ++ks) {                                            \
      bf16x8 af[2], bfr[2];                                                     \
      _Pragma("unroll")                                                         \
      for (int mi = 0; mi < 2; ++mi) {                                          \
        int ar = wr * 64 + mi * 32 + l31;                                       \
        int off = ar * 128 + ((ks * 32 + khb) ^ ((ar & 7) << 4));               \
        af[mi] = *(const bf16x8*)((const char*)As + off);                       \
      }                                                                         \
      _Pragma("unroll")                                                         \
      for (int nj = 0; nj < 2; ++nj) {                                          \
        int br = wc * 64 + nj * 32 + l31;                                       \
        int off = br * 128 + ((ks * 32 + khb) ^ ((br & 7) << 4));               \
        bfr[nj] = *(const bf16x8*)((const char*)Bs + off);                      \
      }                                                                         \
      _Pragma("unroll")                                                         \
      for (int mi = 0; mi < 2; ++mi)                                            \
        _Pragma("unroll")                                                       \
        for (int nj = 0; nj < 2; ++nj)                                          \
          acc[mi][nj] = MFMA32(af[mi], bfr[nj], acc[mi][nj]);                   \
    }                                                                           \
    __syncthreads();                                                            \
  }

// ---------------------------------------------------------------------------
// Fused QKV GEMM: C[4096,5120], grid = 1280, XCD 2D chunk 16x10.
// ---------------------------------------------------------------------------
__global__ __launch_bounds__(256)
void qkv_gemm_kernel(const ushort_t* __restrict__ A,
                     const ushort_t* __restrict__ Wq, const ushort_t* __restrict__ Wk,
                     const ushort_t* __restrict__ Wv,
                     const float* __restrict__ bq, const float* __restrict__ bk,
                     const float* __restrict__ bv, ushort_t* __restrict__ C)
{
  __shared__ __attribute__((aligned(16))) ushort_t As[128 * 64];
  __shared__ __attribute__((aligned(16))) ushort_t Bs[128 * 64];
  const int tid = threadIdx.x;
  const int lane = tid & 63;
  const int wv_ = tid >> 6;
  const int wr = wv_ >> 1, wc = wv_ & 1;
  const int x = blockIdx.x & 7;
  const int li = blockIdx.x >> 3;
  const int bm = ((x & 1) << 4) | (li & 15);
  const int bn = (x >> 1) * 10 + (li >> 4);

  const ushort_t* Wsrc; const float* bsrc; int nloc;
  if (bn < 24)      { Wsrc = Wq; bsrc = bq; nloc = bn << 7; }
  else if (bn < 32) { Wsrc = Wk; bsrc = bk; nloc = (bn - 24) << 7; }
  else              { Wsrc = Wv; bsrc = bv; nloc = (bn - 32) << 7; }

  const size_t rowA0 = (size_t)bm * 128;
  const ushort_t* Wrow = Wsrc + (size_t)nloc * 3072;

  GEMM_BODY32(A, Wrow, 3072)

  // epilogue: 32x32 C/D layout col=l31, row=(r&3)+8*(r>>2)+4*(lane>>5)
  const int rhi = (lane >> 5) << 2;
#pragma unroll
  for (int nj = 0; nj < 2; ++nj) {
    int cl = wc * 64 + nj * 32 + l31;
    float bvl = bsrc[nloc + cl];
    int col = bn * 128 + cl;
#pragma unroll
    for (int mi = 0; mi < 2; ++mi) {
      int row0 = bm * 128 + wr * 64 + mi * 32 + rhi;
#pragma unroll
      for (int r = 0; r < 16; ++r) {
        int rowl = (r & 3) + 8 * (r >> 2);
        C[(size_t)(row0 + rowl) * 5120 + col] = f2bf(acc[mi][nj][r] + bvl);
      }
    }
  }
}

// ---------------------------------------------------------------------------
// Generic single-weight GEMM (out-proj). XCD 2D chunk 16 x cbn.
// ---------------------------------------------------------------------------
template <bool OUT_F32>
__global__ __launch_bounds__(256)
void gemm_bt_kernel(const ushort_t* __restrict__ A, const ushort_t* __restrict__ W,
                    const float* __restrict__ bias, void* __restrict__ Cv,
                    int N, int Kd, int cbn)
{
  __shared__ __attribute__((aligned(16))) ushort_t As[128 * 64];
  __shared__ __attribute__((aligned(16))) ushort_t Bs[128 * 64];
  const int tid = threadIdx.x;
  const int lane = tid & 63;
  const int wv_ = tid >> 6;
  const int wr = wv_ >> 1, wc = wv_ & 1;
  const int x = blockIdx.x & 7;
  const int li = blockIdx.x >> 3;
  const int bm = ((x & 1) << 4) | (li & 15);
  const int bn = (x >> 1) * cbn + (li >> 4);

  const size_t rowA0 = (size_t)bm * 128;
  const ushort_t* Wrow = W + (size_t)(bn * 128) * Kd;

  GEMM_BODY32(A, Wrow, Kd)

  const int rhi = (lane >> 5) << 2;
#pragma unroll
  for (int nj = 0; nj < 2; ++nj) {
    int col = bn * 128 + wc * 64 + nj * 32 + l31;
    float bvl = bias[col];
#pragma unroll
    for (int mi = 0; mi < 2; ++mi) {
      int row0 = bm * 128 + wr * 64 + mi * 32 + rhi;
#pragma unroll
      for (int r = 0; r < 16; ++r) {
        int rowl = (r & 3) + 8 * (r >> 2);
        float v = acc[mi][nj][r] + bvl;
        if (OUT_F32) ((float*)Cv)[(size_t)(row0 + rowl) * N + col] = v;
        else         ((ushort_t*)Cv)[(size_t)(row0 + rowl) * N + col] = f2bf(v);
      }
    }
  }
}

// ---------------------------------------------------------------------------
// Flash attention (round-10, frozen): swapped QK^T, dbuf-K gload_lds, V-reg
// transpose, in-register exp2 softmax + defer-max, shfl-P, unpaired grid.
// ---------------------------------------------------------------------------
#define NHEADS 24
#define GRP 3
#define SEQ 2048
#define QSCL 0.12751745f   // HD^-0.5 * log2(e)
#define DTHR 8.0f          // defer-max threshold (exp2 domain): P <= 2^8

__global__ __launch_bounds__(256)
void attn_kernel(const ushort_t* __restrict__ QKV, ushort_t* __restrict__ O)
{
  __shared__ __attribute__((aligned(16))) ushort_t Kl[2][64 * 128]; // swizzled [kv][d]
  __shared__ __attribute__((aligned(16))) ushort_t Vt[128 * 64];    // swizzled [d][kv]

  const int tid = threadIdx.x;
  const int lane = tid & 63;
  const int wv = tid >> 6;
  const int l15 = lane & 15, lg = lane >> 4;
  const int bh = blockIdx.x;
  const int qb = 31 - blockIdx.y;      // longest blocks dispatch first
  const int b = bh / NHEADS, h = bh % NHEADS;
  const int kvh = h / GRP;
  const size_t kbase = (size_t)b * SEQ * 5120 + 3072 + (size_t)kvh * 128;
  const size_t vbase = kbase + 1024;
  const int q0 = qb * 64;

  const int kv4 = (tid & 15) * 4;      // V staging: 4 kv rows x 8 d per thread
  const int d8 = (tid >> 4) * 8;
  const int a_sel = lg >> 1;
  const int s0l = (lane & 15) + 32 * (lg & 1);

  // ---- prologue: K(0) -> Kl[0] (async), V(0) -> regs ----
#pragma unroll
  for (int i = 0; i < 4; ++i) {
    int o = (i * 256 + tid) * 16;
    int row = o >> 8;
    int src = (o & 255) ^ ((row & 7) << 4);
    gload_lds16(QKV + kbase + (size_t)row * 5120 + (src >> 1), (char*)&Kl[0][0] + o);
  }
  uint4 vr0, vr1, vr2, vr3;
  {
    const ushort_t* vg = QKV + vbase + (size_t)kv4 * 5120 + d8;
    vr0 = *(const uint4*)(vg);
    vr1 = *(const uint4*)(vg + 5120);
    vr2 = *(const uint4*)(vg + 10240);
    vr3 = *(const uint4*)(vg + 15360);
  }

  // Q fragments, pre-scaled by SCALE*log2e
  bf16x8 qf[4];
  {
    const ushort_t* qg = QKV + (size_t)(b * SEQ + q0 + wv * 16 + l15) * 5120 + h * 128 + lg * 8;
#pragma unroll
    for (int c = 0; c < 4; ++c) {
      bf16x8 q = *(const bf16x8*)(qg + c * 32);
#pragma unroll
      for (int e = 0; e < 8; ++e) q[e] = (__bf16)((float)q[e] * QSCL);
      qf[c] = q;
    }
  }

  float m_st = -1e30f, l_st = 0.f;
  f32x4 accO[8] = {};

  for (int t = 0; t <= qb; ++t) {
    const int cur = t & 1;
    // ---- V(t) regs -> Vt (transposed, swizzled) ----
    {
      union { uint4 u; ushort_t s[8]; } L0, L1, L2, L3;
      L0.u = vr0; L1.u = vr1; L2.u = vr2; L3.u = vr3;
#pragma unroll
      for (int dd = 0; dd < 8; ++dd) {
        int d = d8 + dd;
        uint2 w;
        w.x = (uint32)L0.s[dd] | ((uint32)L1.s[dd] << 16);
        w.y = (uint32)L2.s[dd] | ((uint32)L3.s[dd] << 16);
        int swz = ((d & 7) ^ ((d >> 3) & 3)) << 4;
        int off = (d * 128 + kv4 * 2) ^ swz;
        *(uint2*)((char*)Vt + off) = w;
      }
    }
    asm volatile("s_waitcnt lgkmcnt(0)" ::: "memory");
    __builtin_amdgcn_s_barrier();      // Kl[cur] + Vt ready; no vmcnt drain

    // ---- prefetch tile t+1 across the compute phase ----
    if (t < qb) {
      const int kvn = (t + 1) * 64;
#pragma unroll
      for (int i = 0; i < 4; ++i) {
        int o = (i * 256 + tid) * 16;
        int row = o >> 8;
        int src = (o & 255) ^ ((row & 7) << 4);
        gload_lds16(QKV + kbase + (size_t)(kvn + row) * 5120 + (src >> 1),
                    (char*)&Kl[cur ^ 1][0] + o);
      }
      const ushort_t* vg = QKV + vbase + (size_t)(kvn + kv4) * 5120 + d8;
      vr0 = *(const uint4*)(vg);
      vr1 = *(const uint4*)(vg + 5120);
      vr2 = *(const uint4*)(vg + 10240);
      vr3 = *(const uint4*)(vg + 15360);
    }

    // ---- QK^T swapped: s[n] = S^T tile ----
    f32x4 s[4];
    __builtin_amdgcn_s_setprio(1);
#pragma unroll
    for (int n = 0; n < 4; ++n) {
      f32x4 z = {0.f, 0.f, 0.f, 0.f};
      s[n] = z;
#pragma unroll
      for (int c = 0; c < 4; ++c) {
        int row = n * 16 + l15;
        int boff = (row * 256 + c * 64 + lg * 16) ^ ((row & 7) << 4);
        bf16x8 kf = *(const bf16x8*)((const char*)Kl[cur] + boff);
        s[n] = MFMA16(kf, qf[c], s[n]);   // A=K, B=Q -> S^T
      }
    }
    __builtin_amdgcn_s_setprio(0);

    // causal mask (diag tile): kv = 16n+4lg+r vs q-rel = wv*16+l15
    if (t == qb) {
      const int qg_ = wv * 16 + l15;
#pragma unroll
      for (int n = 0; n < 4; ++n)
#pragma unroll
        for (int r = 0; r < 4; ++r)
          if (n * 16 + lg * 4 + r > qg_) s[n][r] = -1e9f;
    }

    // ---- softmax (exp2 domain) with defer-max (T13) ----
    float mx = fmaxf(fmaxf(fmaxf(s[0][0], s[0][1]), fmaxf(s[0][2], s[0][3])),
                     fmaxf(fmaxf(s[1][0], s[1][1]), fmaxf(s[1][2], s[1][3])));
    mx = fmaxf(mx, fmaxf(fmaxf(fmaxf(s[2][0], s[2][1]), fmaxf(s[2][2], s[2][3])),
                         fmaxf(fmaxf(s[3][0], s[3][1]), fmaxf(s[3][2], s[3][3]))));
    mx = fmaxf(mx, __shfl_xor(mx, 16, 64));
    mx = fmaxf(mx, __shfl_xor(mx, 32, 64));

    if (!__all(mx <= m_st + DTHR)) {   // wave-uniform rescale (rare after tile 0)
      const float mnew = fmaxf(m_st, mx);
      const float alpha = __builtin_amdgcn_exp2f(m_st - mnew);
      m_st = mnew;
      l_st *= alpha;
#pragma unroll
      for (int j = 0; j < 8; ++j)
#pragma unroll
        for (int r = 0; r < 4; ++r) accO[j][r] *= alpha;
    }

    float rsum = 0.f;
    uint32 dwA[4], dwB[4];
#pragma unroll
    for (int n = 0; n < 4; ++n) {
      float p0 = __builtin_amdgcn_exp2f(s[n][0] - m_st);
      float p1 = __builtin_amdgcn_exp2f(s[n][1] - m_st);
      float p2 = __builtin_amdgcn_exp2f(s[n][2] - m_st);
      float p3 = __builtin_amdgcn_exp2f(s[n][3] - m_st);
      rsum += (p0 + p1) + (p2 + p3);
      dwA[n] = (uint32)f2bf(p0) | ((uint32)f2bf(p1) << 16);
      dwB[n] = (uint32)f2bf(p2) | ((uint32)f2bf(p3) << 16);
    }
    rsum += __shfl_xor(rsum, 16, 64);
    rsum += __shfl_xor(rsum, 32, 64);
    l_st += rsum;

    // ---- PV: accO[j] += mfma(Vt-frag, P^T-frag) ----
#pragma unroll
    for (int c = 0; c < 2; ++c) {
      uint32 xA0 = __shfl((int)dwA[2 * c],     s0l,      64);
      uint32 xB0 = __shfl((int)dwB[2 * c],     s0l,      64);
      uint32 xA1 = __shfl((int)dwA[2 * c + 1], s0l,      64);
      uint32 xB1 = __shfl((int)dwB[2 * c + 1], s0l,      64);
      uint32 yA0 = __shfl((int)dwA[2 * c],     s0l + 16, 64);
      uint32 yB0 = __shfl((int)dwB[2 * c],     s0l + 16, 64);
      uint32 yA1 = __shfl((int)dwA[2 * c + 1], s0l + 16, 64);
      uint32 yB1 = __shfl((int)dwB[2 * c + 1], s0l + 16, 64);
      union { uint4 u; bf16x8 v; } pb;
      pb.u.x = a_sel ? xA1 : xA0;
      pb.u.y = a_sel ? xB1 : xB0;
      pb.u.z = a_sel ? yA1 : yA0;
      pb.u.w = a_sel ? yB1 : yB0;
      __builtin_amdgcn_s_setprio(1);
#pragma unroll
      for (int j = 0; j < 8; ++j) {
        int d = j * 16 + l15;
        int swz = ((d & 7) ^ ((d >> 3) & 3)) << 4;
        int off = (d * 128 + c * 64 + lg * 16) ^ swz;
        bf16x8 vf = *(const bf16x8*)((const char*)Vt + off);
        accO[j] = MFMA16(vf, pb.v, accO[j]);  // A=V^T, B=P^T -> O^T
      }
      __builtin_amdgcn_s_setprio(0);
    }
    __builtin_amdgcn_s_barrier();   // all waves done reading Kl[cur]/Vt
  }

  // ---- epilogue: O^T layout (d = 16j+4lg+r, q col = l15) ----
  const float inv = 1.0f / l_st;
  ushort_t* og = O + (size_t)(b * SEQ + q0 + wv * 16 + l15) * 3072 + h * 128 + lg * 4;
#pragma unroll
  for (int j = 0; j < 8; ++j) {
    union { uint2 u; ushort_t s[4]; } w;
    w.s[0] = f2bf(accO[j][0] * inv);
    w.s[1] = f2bf(accO[j][1] * inv);
    w.s[2] = f2bf(accO[j][2] * inv);
    w.s[3] = f2bf(accO[j][3] * inv);
    *(uint2*)(og + j * 16) = w.u;
  }
}

// ---------------------------------------------------------------------------
extern "C" void kernel_launch(void* const* d_in, const int* in_sizes, int n_in,
                              void* d_out, int out_size, void* d_ws, size_t ws_size,
                              hipStream_t stream) {
  const float* hs = (const float*)d_in[0];
  // d_in[1] = attention_mask (causal by construction; applied analytically)
  const float* Wq = (const float*)d_in[2];
  const float* bq = (const float*)d_in[3];
  const float* Wk = (const float*)d_in[4];
  const float* bk = (const float*)d_in[5];
  const float* Wv = (const float*)d_in[6];
  const float* bv = (const float*)d_in[7];
  const float* Wd = (const float*)d_in[8];
  const float* bd = (const float*)d_in[9];
  float* out = (float*)d_out;

  const size_t N_HS = (size_t)4096 * 3072;
  const size_t N_WQ = (size_t)3072 * 3072;
  const size_t N_WK = (size_t)1024 * 3072;

  ushort_t* hs_bf = (ushort_t*)d_ws;
  ushort_t* Wq_bf = hs_bf + N_HS;
  ushort_t* Wk_bf = Wq_bf + N_WQ;
  ushort_t* Wv_bf = Wk_bf + N_WK;
  ushort_t* Wd_bf = Wv_bf + N_WK;
  ushort_t* QKVw  = Wd_bf + N_WQ;             // [4096, 5120]
  ushort_t* Cw    = hs_bf;                    // ctx aliases hs_bf

  cvt5_kernel<<<dim3(2048), dim3(256), 0, stream>>>(hs, Wq, Wk, Wv, Wd, hs_bf);
  qkv_gemm_kernel<<<dim3(1280), dim3(256), 0, stream>>>(hs_bf, Wq_bf, Wk_bf, Wv_bf,
                                                        bq, bk, bv, QKVw);
  attn_kernel<<<dim3(48, 32), dim3(256), 0, stream>>>(QKVw, Cw);
  gemm_bt_kernel<true><<<dim3(24 * 32), dim3(256), 0, stream>>>(Cw, Wd_bf, bd, out,
                                                                3072, 3072, 6);
}

// Round 16
// 367.899 us; speedup vs baseline: 1.0816x; 1.0323x over previous
//
#include <hip/hip_runtime.h>

typedef unsigned short ushort_t;
typedef unsigned int uint32;
typedef __bf16 bf16x8 __attribute__((ext_vector_type(8)));
typedef float f32x4 __attribute__((ext_vector_type(4)));
typedef float f32x16 __attribute__((ext_vector_type(16)));

#define MFMA16(a, b, c) __builtin_amdgcn_mfma_f32_16x16x32_bf16((a), (b), (c), 0, 0, 0)
#define MFMA32(a, b, c) __builtin_amdgcn_mfma_f32_32x32x16_bf16((a), (b), (c), 0, 0, 0)

__device__ __forceinline__ ushort_t f2bf(float f) {
  union { float f; uint32 u; } c; c.f = f;
  uint32 u = c.u;
  u += 0x7fffu + ((u >> 16) & 1u);   // round-to-nearest-even
  return (ushort_t)(u >> 16);
}

// async global->LDS, 16B per lane. LDS dest must be wave-uniform base + lane*16.
__device__ __forceinline__ void gload_lds16(const void* g, void* l) {
  __builtin_amdgcn_global_load_lds(
      (const __attribute__((address_space(1))) void*)g,
      (__attribute__((address_space(3))) void*)l, 16, 0, 0);
}

// ---------------------------------------------------------------------------
// Fused fp32->bf16 convert of all 5 tensors (outputs contiguous in ws).
// ---------------------------------------------------------------------------
__global__ __launch_bounds__(256)
void cvt5_kernel(const float* __restrict__ p0, const float* __restrict__ p1,
                 const float* __restrict__ p2, const float* __restrict__ p3,
                 const float* __restrict__ p4, ushort_t* __restrict__ out) {
  const size_t B0 = 12582912;              // hs        [4096x3072]
  const size_t B1 = B0 + 9437184;          // Wq        [3072x3072]
  const size_t B2 = B1 + 3145728;          // Wk        [1024x3072]
  const size_t B3 = B2 + 3145728;          // Wv        [1024x3072]
  const size_t B4 = B3 + 9437184;          // Wd        [3072x3072]
  const size_t step = (size_t)gridDim.x * 256 * 4;
  for (size_t g = ((size_t)blockIdx.x * 256 + threadIdx.x) * 4; g < B4; g += step) {
    const float* src; size_t off;
    if (g < B0)      { src = p0; off = 0;  }
    else if (g < B1) { src = p1; off = B0; }
    else if (g < B2) { src = p2; off = B1; }
    else if (g < B3) { src = p3; off = B2; }
    else             { src = p4; off = B3; }
    float4 v = *(const float4*)(src + (g - off));
    union { uint2 u; ushort_t s[4]; } p;
    p.s[0] = f2bf(v.x); p.s[1] = f2bf(v.y);
    p.s[2] = f2bf(v.z); p.s[3] = f2bf(v.w);
    *(uint2*)(out + g) = p.u;
  }
}

// ===========================================================================
// 2-phase GEMM body, 32x32x16 MFMA (frozen from round 15): 128x128 tile,
// BK=64, 4 waves (2x2), per-wave 64x64 = 2x2 tiles of 32x32.
// ===========================================================================
#define GEMM_BODY32(ABASE, WROWBASE, KD)                                        \
  f32x16 acc[2][2] = {};                                                        \
  const int l31 = lane & 31;                                                    \
  const int khb = (lane >> 5) << 4;  /* k-half byte offset: 0 or 16 */          \
  const int nk = (KD) >> 6;                                                     \
  for (int kt = 0; kt < nk; ++kt) {                                             \
    _Pragma("unroll")                                                           \
    for (int i = 0; i < 4; ++i) {                                               \
      int o = (i * 256 + tid) * 16;                                             \
      int row = o >> 7;                                                         \
      int src = (o & 127) ^ ((row & 7) << 4);                                   \
      gload_lds16(ABASE + (rowA0 + row) * (KD) + kt * 64 + (src >> 1),          \
                  (char*)As + o);                                               \
      gload_lds16(WROWBASE + (size_t)row * (KD) + kt * 64 + (src >> 1),         \
                  (char*)Bs + o);                                               \
    }                                                                           \
    __syncthreads();                                                            \
    _Pragma("unroll")                                                           \
    for (int ks = 0; ks < 4; ++ks) {                                            \
      bf16x8 af[2], bfr[2];                                                     \
      _Pragma("unroll")                                                         \
      for (int mi = 0; mi < 2; ++mi) {                                          \
        int ar = wr * 64 + mi * 32 + l31;                                       \
        int off = ar * 128 + ((ks * 32 + khb) ^ ((ar & 7) << 4));               \
        af[mi] = *(const bf16x8*)((const char*)As + off);                       \
      }                                                                         \
      _Pragma("unroll")                                                         \
      for (int nj = 0; nj < 2; ++nj) {                                          \
        int br = wc * 64 + nj * 32 + l31;                                       \
        int off = br * 128 + ((ks * 32 + khb) ^ ((br & 7) << 4));               \
        bfr[nj] = *(const bf16x8*)((const char*)Bs + off);                      \
      }                                                                         \
      _Pragma("unroll")                                                         \
      for (int mi = 0; mi < 2; ++mi)                                            \
        _Pragma("unroll")                                                       \
        for (int nj = 0; nj < 2; ++nj)                                          \
          acc[mi][nj] = MFMA32(af[mi], bfr[nj], acc[mi][nj]);                   \
    }                                                                           \
    __syncthreads();                                                            \
  }

// ---------------------------------------------------------------------------
// Fused QKV GEMM (frozen): C[4096,5120], grid = 1280, XCD 2D chunk 16x10.
// ---------------------------------------------------------------------------
__global__ __launch_bounds__(256)
void qkv_gemm_kernel(const ushort_t* __restrict__ A,
                     const ushort_t* __restrict__ Wq, const ushort_t* __restrict__ Wk,
                     const ushort_t* __restrict__ Wv,
                     const float* __restrict__ bq, const float* __restrict__ bk,
                     const float* __restrict__ bv, ushort_t* __restrict__ C)
{
  __shared__ __attribute__((aligned(16))) ushort_t As[128 * 64];
  __shared__ __attribute__((aligned(16))) ushort_t Bs[128 * 64];
  const int tid = threadIdx.x;
  const int lane = tid & 63;
  const int wv_ = tid >> 6;
  const int wr = wv_ >> 1, wc = wv_ & 1;
  const int x = blockIdx.x & 7;
  const int li = blockIdx.x >> 3;
  const int bm = ((x & 1) << 4) | (li & 15);
  const int bn = (x >> 1) * 10 + (li >> 4);

  const ushort_t* Wsrc; const float* bsrc; int nloc;
  if (bn < 24)      { Wsrc = Wq; bsrc = bq; nloc = bn << 7; }
  else if (bn < 32) { Wsrc = Wk; bsrc = bk; nloc = (bn - 24) << 7; }
  else              { Wsrc = Wv; bsrc = bv; nloc = (bn - 32) << 7; }

  const size_t rowA0 = (size_t)bm * 128;
  const ushort_t* Wrow = Wsrc + (size_t)nloc * 3072;

  GEMM_BODY32(A, Wrow, 3072)

  // epilogue: 32x32 C/D layout col=l31, row=(r&3)+8*(r>>2)+4*(lane>>5)
  const int rhi = (lane >> 5) << 2;
#pragma unroll
  for (int nj = 0; nj < 2; ++nj) {
    int cl = wc * 64 + nj * 32 + l31;
    float bvl = bsrc[nloc + cl];
    int col = bn * 128 + cl;
#pragma unroll
    for (int mi = 0; mi < 2; ++mi) {
      int row0 = bm * 128 + wr * 64 + mi * 32 + rhi;
#pragma unroll
      for (int r = 0; r < 16; ++r) {
        int rowl = (r & 3) + 8 * (r >> 2);
        C[(size_t)(row0 + rowl) * 5120 + col] = f2bf(acc[mi][nj][r] + bvl);
      }
    }
  }
}

// ---------------------------------------------------------------------------
// Generic single-weight GEMM (frozen, out-proj). XCD 2D chunk 16 x cbn.
// ---------------------------------------------------------------------------
template <bool OUT_F32>
__global__ __launch_bounds__(256)
void gemm_bt_kernel(const ushort_t* __restrict__ A, const ushort_t* __restrict__ W,
                    const float* __restrict__ bias, void* __restrict__ Cv,
                    int N, int Kd, int cbn)
{
  __shared__ __attribute__((aligned(16))) ushort_t As[128 * 64];
  __shared__ __attribute__((aligned(16))) ushort_t Bs[128 * 64];
  const int tid = threadIdx.x;
  const int lane = tid & 63;
  const int wv_ = tid >> 6;
  const int wr = wv_ >> 1, wc = wv_ & 1;
  const int x = blockIdx.x & 7;
  const int li = blockIdx.x >> 3;
  const int bm = ((x & 1) << 4) | (li & 15);
  const int bn = (x >> 1) * cbn + (li >> 4);

  const size_t rowA0 = (size_t)bm * 128;
  const ushort_t* Wrow = W + (size_t)(bn * 128) * Kd;

  GEMM_BODY32(A, Wrow, Kd)

  const int rhi = (lane >> 5) << 2;
#pragma unroll
  for (int nj = 0; nj < 2; ++nj) {
    int col = bn * 128 + wc * 64 + nj * 32 + l31;
    float bvl = bias[col];
#pragma unroll
    for (int mi = 0; mi < 2; ++mi) {
      int row0 = bm * 128 + wr * 64 + mi * 32 + rhi;
#pragma unroll
      for (int r = 0; r < 16; ++r) {
        int rowl = (r & 3) + 8 * (r >> 2);
        float v = acc[mi][nj][r] + bvl;
        if (OUT_F32) ((float*)Cv)[(size_t)(row0 + rowl) * N + col] = v;
        else         ((ushort_t*)Cv)[(size_t)(row0 + rowl) * N + col] = f2bf(v);
      }
    }
  }
}

// ---------------------------------------------------------------------------
// Flash attention v6: round-10 structure + K-row LDS permutation that makes
// the PV B-fragment LANE-LOCAL (zero shuffles).
//   Staging: LDS row u holds global K row g(u) = 8*((u>>2)&3) + 4*((u>>4)&1)
//            + (u&3) + 32*(u>>5)  (bijective on 0..63).
//   S^T reg (n,r), lane group lg then holds kv = 32*(n>>1) + 8*lg + 4*(n&1) + r
//   -> PV B-frag k = lg*8+j needs kv = c*32+lg*8+j = s[(c<<1)|(j>>2)][j&3]. Local.
// Native (__bf16) casts for P-pack and O-store (v_cvt_pk_bf16_f32, RNE).
// ---------------------------------------------------------------------------
#define NHEADS 24
#define GRP 3
#define SEQ 2048
#define QSCL 0.12751745f   // HD^-0.5 * log2(e)
#define DTHR 8.0f          // defer-max threshold (exp2 domain): P <= 2^8

__device__ __forceinline__ int kperm(int u) {
  return 8 * ((u >> 2) & 3) + 4 * ((u >> 4) & 1) + (u & 3) + 32 * (u >> 5);
}

__global__ __launch_bounds__(256)
void attn_kernel(const ushort_t* __restrict__ QKV, ushort_t* __restrict__ O)
{
  __shared__ __attribute__((aligned(16))) ushort_t Kl[2][64 * 128]; // swizzled, row-permuted
  __shared__ __attribute__((aligned(16))) ushort_t Vt[128 * 64];    // swizzled [d][kv]

  const int tid = threadIdx.x;
  const int lane = tid & 63;
  const int wv = tid >> 6;
  const int l15 = lane & 15, lg = lane >> 4;
  const int bh = blockIdx.x;
  const int qb = 31 - blockIdx.y;      // longest blocks dispatch first
  const int b = bh / NHEADS, h = bh % NHEADS;
  const int kvh = h / GRP;
  const size_t kbase = (size_t)b * SEQ * 5120 + 3072 + (size_t)kvh * 128;
  const size_t vbase = kbase + 1024;
  const int q0 = qb * 64;

  const int kv4 = (tid & 15) * 4;      // V staging: 4 kv rows x 8 d per thread
  const int d8 = (tid >> 4) * 8;

  // ---- prologue: K(0) -> Kl[0] (async, row-permuted), V(0) -> regs ----
#pragma unroll
  for (int i = 0; i < 4; ++i) {
    int o = (i * 256 + tid) * 16;
    int row = o >> 8;
    int src = (o & 255) ^ ((row & 7) << 4);
    gload_lds16(QKV + kbase + (size_t)kperm(row) * 5120 + (src >> 1),
                (char*)&Kl[0][0] + o);
  }
  uint4 vr0, vr1, vr2, vr3;
  {
    const ushort_t* vg = QKV + vbase + (size_t)kv4 * 5120 + d8;
    vr0 = *(const uint4*)(vg);
    vr1 = *(const uint4*)(vg + 5120);
    vr2 = *(const uint4*)(vg + 10240);
    vr3 = *(const uint4*)(vg + 15360);
  }

  // Q fragments, pre-scaled by SCALE*log2e
  bf16x8 qf[4];
  {
    const ushort_t* qg = QKV + (size_t)(b * SEQ + q0 + wv * 16 + l15) * 5120 + h * 128 + lg * 8;
#pragma unroll
    for (int c = 0; c < 4; ++c) {
      bf16x8 q = *(const bf16x8*)(qg + c * 32);
#pragma unroll
      for (int e = 0; e < 8; ++e) q[e] = (__bf16)((float)q[e] * QSCL);
      qf[c] = q;
    }
  }

  float m_st = -1e30f, l_st = 0.f;
  f32x4 accO[8] = {};

  for (int t = 0; t <= qb; ++t) {
    const int cur = t & 1;
    // ---- V(t) regs -> Vt (transposed, swizzled) ----
    {
      union { uint4 u; ushort_t s[8]; } L0, L1, L2, L3;
      L0.u = vr0; L1.u = vr1; L2.u = vr2; L3.u = vr3;
#pragma unroll
      for (int dd = 0; dd < 8; ++dd) {
        int d = d8 + dd;
        uint2 w;
        w.x = (uint32)L0.s[dd] | ((uint32)L1.s[dd] << 16);
        w.y = (uint32)L2.s[dd] | ((uint32)L3.s[dd] << 16);
        int swz = ((d & 7) ^ ((d >> 3) & 3)) << 4;
        int off = (d * 128 + kv4 * 2) ^ swz;
        *(uint2*)((char*)Vt + off) = w;
      }
    }
    asm volatile("s_waitcnt lgkmcnt(0)" ::: "memory");
    __builtin_amdgcn_s_barrier();      // Kl[cur] + Vt ready; no vmcnt drain

    // ---- prefetch tile t+1 across the compute phase ----
    if (t < qb) {
      const int kvn = (t + 1) * 64;
#pragma unroll
      for (int i = 0; i < 4; ++i) {
        int o = (i * 256 + tid) * 16;
        int row = o >> 8;
        int src = (o & 255) ^ ((row & 7) << 4);
        gload_lds16(QKV + kbase + (size_t)(kvn + kperm(row)) * 5120 + (src >> 1),
                    (char*)&Kl[cur ^ 1][0] + o);
      }
      const ushort_t* vg = QKV + vbase + (size_t)(kvn + kv4) * 5120 + d8;
      vr0 = *(const uint4*)(vg);
      vr1 = *(const uint4*)(vg + 5120);
      vr2 = *(const uint4*)(vg + 10240);
      vr3 = *(const uint4*)(vg + 15360);
    }

    // ---- QK^T swapped: s[n] = S^T tile over PERMUTED kv rows ----
    f32x4 s[4];
    __builtin_amdgcn_s_setprio(1);
#pragma unroll
    for (int n = 0; n < 4; ++n) {
      f32x4 z = {0.f, 0.f, 0.f, 0.f};
      s[n] = z;
#pragma unroll
      for (int c = 0; c < 4; ++c) {
        int row = n * 16 + l15;
        int boff = (row * 256 + c * 64 + lg * 16) ^ ((row & 7) << 4);
        bf16x8 kf = *(const bf16x8*)((const char*)Kl[cur] + boff);
        s[n] = MFMA16(kf, qf[c], s[n]);   // A=K(perm), B=Q -> S^T
      }
    }
    __builtin_amdgcn_s_setprio(0);

    // causal mask (diag tile): reg (n,r) holds kv_rel = 8lg + 4(n&1) + r + 32(n>>1)
    if (t == qb) {
      const int qg_ = wv * 16 + l15;
      const int blg = 8 * lg;
#pragma unroll
      for (int n = 0; n < 4; ++n)
#pragma unroll
        for (int r = 0; r < 4; ++r) {
          int kvr = blg + ((n & 1) << 2) + r + ((n >> 1) << 5);
          if (kvr > qg_) s[n][r] = -1e9f;
        }
    }

    // ---- softmax (exp2 domain) with defer-max (T13); reduce unchanged ----
    float mx = fmaxf(fmaxf(fmaxf(s[0][0], s[0][1]), fmaxf(s[0][2], s[0][3])),
                     fmaxf(fmaxf(s[1][0], s[1][1]), fmaxf(s[1][2], s[1][3])));
    mx = fmaxf(mx, fmaxf(fmaxf(fmaxf(s[2][0], s[2][1]), fmaxf(s[2][2], s[2][3])),
                         fmaxf(fmaxf(s[3][0], s[3][1]), fmaxf(s[3][2], s[3][3]))));
    mx = fmaxf(mx, __shfl_xor(mx, 16, 64));
    mx = fmaxf(mx, __shfl_xor(mx, 32, 64));

    if (!__all(mx <= m_st + DTHR)) {   // wave-uniform rescale (rare after tile 0)
      const float mnew = fmaxf(m_st, mx);
      const float alpha = __builtin_amdgcn_exp2f(m_st - mnew);
      m_st = mnew;
      l_st *= alpha;
#pragma unroll
      for (int j = 0; j < 8; ++j)
#pragma unroll
        for (int r = 0; r < 4; ++r) accO[j][r] *= alpha;
    }

    float rsum = 0.f;
#pragma unroll
    for (int n = 0; n < 4; ++n) {
      s[n][0] = __builtin_amdgcn_exp2f(s[n][0] - m_st);
      s[n][1] = __builtin_amdgcn_exp2f(s[n][1] - m_st);
      s[n][2] = __builtin_amdgcn_exp2f(s[n][2] - m_st);
      s[n][3] = __builtin_amdgcn_exp2f(s[n][3] - m_st);
      rsum += (s[n][0] + s[n][1]) + (s[n][2] + s[n][3]);
    }
    rsum += __shfl_xor(rsum, 16, 64);
    rsum += __shfl_xor(rsum, 32, 64);
    l_st += rsum;

    // ---- PV: P^T fragment is lane-local (kv = 32c + 8lg + j) ----
#pragma unroll
    for (int c = 0; c < 2; ++c) {
      bf16x8 pb;
#pragma unroll
      for (int j = 0; j < 8; ++j)
        pb[j] = (__bf16)s[(c << 1) | (j >> 2)][j & 3];
      __builtin_amdgcn_s_setprio(1);
#pragma unroll
      for (int j = 0; j < 8; ++j) {
        int d = j * 16 + l15;
        int swz = ((d & 7) ^ ((d >> 3) & 3)) << 4;
        int off = (d * 128 + c * 64 + lg * 16) ^ swz;
        bf16x8 vf = *(const bf16x8*)((const char*)Vt + off);
        accO[j] = MFMA16(vf, pb, accO[j]);  // A=V^T, B=P^T -> O^T
      }
      __builtin_amdgcn_s_setprio(0);
    }
    __builtin_amdgcn_s_barrier();   // all waves done reading Kl[cur]/Vt
  }

  // ---- epilogue: O^T layout (d = 16j+4lg+r, q col = l15), native casts ----
  const float inv = 1.0f / l_st;
  ushort_t* og = O + (size_t)(b * SEQ + q0 + wv * 16 + l15) * 3072 + h * 128 + lg * 4;
#pragma unroll
  for (int j = 0; j < 8; ++j) {
    union { __bf16 h[4]; uint2 u; } w;
    w.h[0] = (__bf16)(accO[j][0] * inv);
    w.h[1] = (__bf16)(accO[j][1] * inv);
    w.h[2] = (__bf16)(accO[j][2] * inv);
    w.h[3] = (__bf16)(accO[j][3] * inv);
    *(uint2*)(og + j * 16) = w.u;
  }
}

// ---------------------------------------------------------------------------
extern "C" void kernel_launch(void* const* d_in, const int* in_sizes, int n_in,
                              void* d_out, int out_size, void* d_ws, size_t ws_size,
                              hipStream_t stream) {
  const float* hs = (const float*)d_in[0];
  // d_in[1] = attention_mask (causal by construction; applied analytically)
  const float* Wq = (const float*)d_in[2];
  const float* bq = (const float*)d_in[3];
  const float* Wk = (const float*)d_in[4];
  const float* bk = (const float*)d_in[5];
  const float* Wv = (const float*)d_in[6];
  const float* bv = (const float*)d_in[7];
  const float* Wd = (const float*)d_in[8];
  const float* bd = (const float*)d_in[9];
  float* out = (float*)d_out;

  const size_t N_HS = (size_t)4096 * 3072;
  const size_t N_WQ = (size_t)3072 * 3072;
  const size_t N_WK = (size_t)1024 * 3072;

  ushort_t* hs_bf = (ushort_t*)d_ws;
  ushort_t* Wq_bf = hs_bf + N_HS;
  ushort_t* Wk_bf = Wq_bf + N_WQ;
  ushort_t* Wv_bf = Wk_bf + N_WK;
  ushort_t* Wd_bf = Wv_bf + N_WK;
  ushort_t* QKVw  = Wd_bf + N_WQ;             // [4096, 5120]
  ushort_t* Cw    = hs_bf;                    // ctx aliases hs_bf

  cvt5_kernel<<<dim3(2048), dim3(256), 0, stream>>>(hs, Wq, Wk, Wv, Wd, hs_bf);
  qkv_gemm_kernel<<<dim3(1280), dim3(256), 0, stream>>>(hs_bf, Wq_bf, Wk_bf, Wv_bf,
                                                        bq, bk, bv, QKVw);
  attn_kernel<<<dim3(48, 32), dim3(256), 0, stream>>>(QKVw, Cw);
  gemm_bt_kernel<true><<<dim3(24 * 32), dim3(256), 0, stream>>>(Cw, Wd_bf, bd, out,
                                                                3072, 3072, 6);
}